// Round 16
// baseline (296.724 us; speedup 1.0000x reference)
//
#include <hip/hip_runtime.h>

// ---------------------------------------------------------------------------
// R16: numerics frozen from R6 (PASS, absmax 1.95e-3).
//  - conv2: REVERT R15's oc-split (regressed 270->283) to R13's 16-wide
//    wt + 512-block version.
//  - fc1: model says the invariant ~84us = LDS-read bytes bound
//    (2.12 GB at ~85 B/cyc/CU). Cut bytes/MAC 1.0 -> 0.75 with an 8m x 16n
//    microtile on 128-THREAD blocks (128x128 tile, grid (4,8,15)); LDS
//    22.5 KB -> ~6 blocks/CU co-resident so FMA of one block overlaps LDS of
//    another. Packed LDS (A: 8-groups pad-12; B: 16-groups stride-20) keeps
//    compute reads <=2-way. Chains k-ascending per panel -> bit-identical.
// conv1 / snn_loop unchanged.
// ---------------------------------------------------------------------------

// ---------------------------------------------------------------------------
// Kernel 0: conv2 weight transpose -> 16-wide per-wave K-major (R13 version).
// wt[((g*32+ic)*9+kk)*16 + i] = w[(g*16+i)*288 + ic*9 + kk], g in [0,4).
// ---------------------------------------------------------------------------
__global__ void __launch_bounds__(256) conv2_wt(
    const float* __restrict__ w, float* __restrict__ wt) {
  int tid = blockIdx.x * 256 + threadIdx.x;
  if (tid >= 64 * 288) return;
  int i = tid & 15;
  int node = tid >> 4;
  int kk = node % 9;
  int gic = node / 9;
  int ic = gic & 31, g = gic >> 5;
  wt[tid] = w[(size_t)(g * 16 + i) * 288 + ic * 9 + kk];
}

// ---------------------------------------------------------------------------
// Kernel 1: conv1 (3->32) + bias + ReLU + 2x2 maxpool. UNCHANGED.
// ---------------------------------------------------------------------------
__global__ void __launch_bounds__(256) conv1_pool(
    const float* __restrict__ x, const float* __restrict__ w,
    const float* __restrict__ bias, float* __restrict__ p1) {
  const int b = blockIdx.x;
  __shared__ float sx[3 * 34 * 34];
  const float* xb = x + (size_t)b * 3072;
  for (int i = threadIdx.x; i < 3 * 34 * 34; i += 256) sx[i] = 0.0f;
  __syncthreads();
  for (int i = threadIdx.x; i < 3072; i += 256) {
    int ic = i >> 10, y = (i >> 5) & 31, xx = i & 31;
    sx[ic * 1156 + (y + 1) * 34 + (xx + 1)] = xb[i];
  }
  __syncthreads();

  const int px = threadIdx.x & 15, py = threadIdx.x >> 4;
  float xr[3][4][4];
#pragma unroll
  for (int ic = 0; ic < 3; ic++)
#pragma unroll
    for (int r = 0; r < 4; r++)
#pragma unroll
      for (int c = 0; c < 4; c++)
        xr[ic][r][c] = sx[ic * 1156 + (2 * py + r) * 34 + (2 * px + c)];

  float* outp = p1 + (size_t)b * 8192 + py * 16 + px;
  for (int oc = 0; oc < 32; oc++) {
    const float* wo = w + oc * 27;
    float a0 = 0.0f, a1 = 0.0f, a2 = 0.0f, a3 = 0.0f;
#pragma unroll
    for (int ky = 0; ky < 3; ky++)
#pragma unroll
      for (int kx = 0; kx < 3; kx++)
#pragma unroll
        for (int ic = 0; ic < 3; ic++) {  // ic innermost (HWIO im2col order)
          float wv = wo[ic * 9 + ky * 3 + kx];
          a0 = fmaf(wv, xr[ic][ky][kx], a0);
          a1 = fmaf(wv, xr[ic][ky][kx + 1], a1);
          a2 = fmaf(wv, xr[ic][ky + 1][kx], a2);
          a3 = fmaf(wv, xr[ic][ky + 1][kx + 1], a3);
        }
    float bv = bias[oc];
    a0 = fmaxf(__fadd_rn(a0, bv), 0.0f);
    a1 = fmaxf(__fadd_rn(a1, bv), 0.0f);
    a2 = fmaxf(__fadd_rn(a2, bv), 0.0f);
    a3 = fmaxf(__fadd_rn(a3, bv), 0.0f);
    outp[oc * 256] = fmaxf(fmaxf(a0, a1), fmaxf(a2, a3));
  }
}

// ---------------------------------------------------------------------------
// Kernel 2: conv2 (32->64) + bias + ReLU + pool, K-major 16-wide weights
// (R13 version, 512 blocks). Chain: ky -> kx -> ic (ic fastest).
// ---------------------------------------------------------------------------
__global__ void __launch_bounds__(256) conv2_pool(
    const float* __restrict__ p1, const float* __restrict__ wt,
    const float* __restrict__ bias, float* __restrict__ p2) {
  const int b = blockIdx.x;
  __shared__ float sx[32 * 18 * 18];  // 41472 B
  const float* xb = p1 + (size_t)b * 8192;
  for (int i = threadIdx.x; i < 32 * 18 * 18; i += 256) sx[i] = 0.0f;
  __syncthreads();
  for (int i = threadIdx.x; i < 8192; i += 256) {
    int ic = i >> 8, y = (i >> 4) & 15, xx = i & 15;
    sx[ic * 324 + (y + 1) * 18 + (xx + 1)] = xb[i];
  }
  __syncthreads();

  const int t = threadIdx.x;
  const int px = t & 7, py = (t >> 3) & 7;
  const int g = __builtin_amdgcn_readfirstlane(t >> 6);  // wave 0..3
  const float* wg = wt + (size_t)g * 32 * 9 * 16;        // wave's K-stream

  float acc[16][4];
#pragma unroll
  for (int i = 0; i < 16; i++)
    acc[i][0] = acc[i][1] = acc[i][2] = acc[i][3] = 0.0f;

#pragma unroll
  for (int ky = 0; ky < 3; ky++) {
#pragma unroll
    for (int kx = 0; kx < 3; kx++) {
      const int r0 = (2 * py + ky) * 18 + 2 * px + kx;
      const int r1 = r0 + 18;
#pragma unroll 4
      for (int ic = 0; ic < 32; ic++) {  // ic innermost (chain order)
        float x00 = sx[ic * 324 + r0];
        float x01 = sx[ic * 324 + r0 + 1];
        float x10 = sx[ic * 324 + r1];
        float x11 = sx[ic * 324 + r1 + 1];
        const float* wp = wg + (size_t)(ic * 9 + ky * 3 + kx) * 16;
#pragma unroll
        for (int i = 0; i < 16; i++) {
          float wv = wp[i];  // wave-uniform contiguous -> s_load
          acc[i][0] = fmaf(wv, x00, acc[i][0]);
          acc[i][1] = fmaf(wv, x01, acc[i][1]);
          acc[i][2] = fmaf(wv, x10, acc[i][2]);
          acc[i][3] = fmaf(wv, x11, acc[i][3]);
        }
      }
    }
  }

  float* outb = p2 + (size_t)b * 4096;
#pragma unroll
  for (int i = 0; i < 16; i++) {
    float bv = bias[g * 16 + i];
    float a0 = fmaxf(__fadd_rn(acc[i][0], bv), 0.0f);
    float a1 = fmaxf(__fadd_rn(acc[i][1], bv), 0.0f);
    float a2 = fmaxf(__fadd_rn(acc[i][2], bv), 0.0f);
    float a3 = fmaxf(__fadd_rn(acc[i][3], bv), 0.0f);
    outb[(g * 16 + i) * 64 + py * 8 + px] = fmaxf(fmaxf(a0, a1), fmaxf(a2, a3));
  }
}

// ---------------------------------------------------------------------------
// Kernel 3: fc1 panel GEMM v5. 128 threads, 128x128 tile, 8m x 16n microtile,
// grid (4,8,15). Staging: thread t owns A row m0+t and B row n0+t (16 k's,
// 4x float4 each). Packed LDS: As 16 rows x 192 (8-groups pad 12), Bs 16 x
// 160 (16-groups stride 20, 16B-aligned). Per-thread-k reads: 2+4 b128 for
// 128 MACs = 0.75 B/MAC. Chains strictly k-ascending per kc=288 panel.
// ---------------------------------------------------------------------------
__global__ void __launch_bounds__(128) fc1_panel(
    const float* __restrict__ A,   // h [512,4096]
    const float* __restrict__ W,   // [1000,4096]
    float* __restrict__ part) {    // [15,512,1000]
  __shared__ __align__(16) float As[16][192];  // 12288 B
  __shared__ __align__(16) float Bs[16][160];  // 10240 B
  const int t = threadIdx.x;  // 0..127
  const int m0 = blockIdx.x * 128, n0 = blockIdx.y * 128;
  const int z = blockIdx.z;
  const int k0 = z * 288;
  const int L = (z == 14) ? 64 : 288;

  const int packA = ((t >> 3) * 12) + (t & 7);
  const int packB = ((t >> 4) * 20) + (t & 15);
  const int nr = n0 + t;
  const float* Ap = A + (size_t)(m0 + t) * 4096 + k0;
  const float* Bp = W + (size_t)(nr < 1000 ? nr : 0) * 4096 + k0;
  const int tx = t & 15, ty = t >> 4;  // tx: m-group of 8, ty: n-group of 16

  float acc[8][16];
#pragma unroll
  for (int i = 0; i < 8; i++)
#pragma unroll
    for (int j = 0; j < 16; j++) acc[i][j] = 0.0f;

  for (int kk = 0; kk < L; kk += 16) {
    float4 a0 = *(const float4*)(Ap + 0);
    float4 a1 = *(const float4*)(Ap + 4);
    float4 a2 = *(const float4*)(Ap + 8);
    float4 a3 = *(const float4*)(Ap + 12);
    float4 b0 = *(const float4*)(Bp + 0);
    float4 b1 = *(const float4*)(Bp + 4);
    float4 b2 = *(const float4*)(Bp + 8);
    float4 b3 = *(const float4*)(Bp + 12);
    As[0][packA] = a0.x;  As[1][packA] = a0.y;
    As[2][packA] = a0.z;  As[3][packA] = a0.w;
    As[4][packA] = a1.x;  As[5][packA] = a1.y;
    As[6][packA] = a1.z;  As[7][packA] = a1.w;
    As[8][packA] = a2.x;  As[9][packA] = a2.y;
    As[10][packA] = a2.z; As[11][packA] = a2.w;
    As[12][packA] = a3.x; As[13][packA] = a3.y;
    As[14][packA] = a3.z; As[15][packA] = a3.w;
    Bs[0][packB] = b0.x;  Bs[1][packB] = b0.y;
    Bs[2][packB] = b0.z;  Bs[3][packB] = b0.w;
    Bs[4][packB] = b1.x;  Bs[5][packB] = b1.y;
    Bs[6][packB] = b1.z;  Bs[7][packB] = b1.w;
    Bs[8][packB] = b2.x;  Bs[9][packB] = b2.y;
    Bs[10][packB] = b2.z; Bs[11][packB] = b2.w;
    Bs[12][packB] = b3.x; Bs[13][packB] = b3.y;
    Bs[14][packB] = b3.z; Bs[15][packB] = b3.w;
    __syncthreads();

#pragma unroll 2
    for (int k = 0; k < 16; k++) {
      float4 av0 = *(const float4*)&As[k][tx * 12];
      float4 av1 = *(const float4*)&As[k][tx * 12 + 4];
      float4 bv0 = *(const float4*)&Bs[k][ty * 20];
      float4 bv1 = *(const float4*)&Bs[k][ty * 20 + 4];
      float4 bv2 = *(const float4*)&Bs[k][ty * 20 + 8];
      float4 bv3 = *(const float4*)&Bs[k][ty * 20 + 12];
      float am[8] = {av0.x, av0.y, av0.z, av0.w, av1.x, av1.y, av1.z, av1.w};
      float bn[16] = {bv0.x, bv0.y, bv0.z, bv0.w, bv1.x, bv1.y, bv1.z, bv1.w,
                      bv2.x, bv2.y, bv2.z, bv2.w, bv3.x, bv3.y, bv3.z, bv3.w};
#pragma unroll
      for (int i = 0; i < 8; i++)
#pragma unroll
        for (int j = 0; j < 16; j++)
          acc[i][j] = fmaf(am[i], bn[j], acc[i][j]);
    }
    __syncthreads();
    Ap += 16; Bp += 16;
  }

  float* pp = part + (size_t)z * 512000;
  const int nb = n0 + ty * 16;
#pragma unroll
  for (int i = 0; i < 8; i++) {
    const int m = m0 + tx * 8 + i;
    if (nb + 15 < 1000) {
#pragma unroll
      for (int jj = 0; jj < 4; jj++) {
        float4 v;
        v.x = acc[i][jj * 4 + 0]; v.y = acc[i][jj * 4 + 1];
        v.z = acc[i][jj * 4 + 2]; v.w = acc[i][jj * 4 + 3];
        *(float4*)&pp[(size_t)m * 1000 + nb + jj * 4] = v;
      }
    } else {
#pragma unroll
      for (int j = 0; j < 16; j++) {
        const int n = nb + j;
        if (n < 1000) pp[(size_t)m * 1000 + n] = acc[i][j];
      }
    }
  }
}

// ---------------------------------------------------------------------------
// Kernel 4: fused 10-step SNN. UNCHANGED from R10.
// ---------------------------------------------------------------------------
__global__ void __launch_bounds__(256) snn_loop(
    const float* __restrict__ part,   // [15,512,1000]
    const float* __restrict__ fc1_b,  // [1000]
    const float* __restrict__ fc2_w,  // [10,1000]
    const float* __restrict__ fc2_b,  // [10]
    float* __restrict__ out) {        // [102400]
  const int b = blockIdx.x;
  const int t = threadIdx.x;
  __shared__ float pw[40 * 289];   // 46240 B
  __shared__ float spkp[4 * 289];  //  4624 B

  for (int i = t; i < 40 * 289; i += 256) {
    int chain = i / 289, ii = i - chain * 289;
    int o = chain % 10, c = chain / 10;
    int len = (c == 3) ? 136 : 288;
    pw[i] = (ii < len) ? fc2_w[o * 1000 + c * 288 + ii] : 0.0f;
  }

  float cur1[4], mem1[4];
#pragma unroll
  for (int q = 0; q < 4; q++) {
    int j = t + q * 256;
    float c = 0.0f;
    if (j < 1000) {
      const float* pb = part + (size_t)b * 1000 + j;
      float tot = pb[0];
#pragma unroll
      for (int p = 1; p < 15; p++)
        tot = __fadd_rn(tot, pb[(size_t)p * 512000]);
      c = __fadd_rn(tot, fc1_b[j]);
    }
    cur1[q] = c;
    mem1[q] = 0.0f;
  }
  float m2 = 0.0f;  // live only for t < 10
  __syncthreads();

  const int o4 = t % 10, c4 = t / 10;  // chain (o4, c4) for t < 40
  const float* wch = &pw[(c4 * 10 + o4) * 289];
  const float* sch = &spkp[c4 * 289];

  for (int s = 0; s < 10; s++) {
#pragma unroll
    for (int q = 0; q < 4; q++) {
      int j = t + q * 256;
      float m = mem1[q];
      float reset = (m > 1.0f) ? 1.0f : 0.0f;
      float t1 = __fmul_rn(0.95f, m);
      float t2 = __fadd_rn(t1, cur1[q]);
      m = __fsub_rn(t2, reset);
      mem1[q] = m;
      if (j < 1000) {
        int pc = (j >= 864) ? 3 : ((j >= 576) ? 2 : ((j >= 288) ? 1 : 0));
        spkp[pc * 289 + (j - pc * 288)] = (m > 1.0f) ? 1.0f : 0.0f;
      }
    }
    __syncthreads();

    float acc = 0.0f;
    if (t < 40) {
      if (c4 < 3) {
#pragma unroll 16
        for (int i = 0; i < 288; i++) acc = fmaf(sch[i], wch[i], acc);
      } else {
#pragma unroll 17
        for (int i = 0; i < 136; i++) acc = fmaf(sch[i], wch[i], acc);
      }
    }

    if (t < 64) {
      float p0 = __shfl(acc, o4, 64);
      float p1 = __shfl(acc, 10 + o4, 64);
      float p2 = __shfl(acc, 20 + o4, 64);
      float p3 = __shfl(acc, 30 + o4, 64);
      if (t < 10) {
        float tot = p0;
        tot = __fadd_rn(tot, p1);
        tot = __fadd_rn(tot, p2);
        tot = __fadd_rn(tot, p3);
        float c2 = __fadd_rn(tot, fc2_b[t]);
        float r2 = (m2 > 1.0f) ? 1.0f : 0.0f;
        float u1 = __fmul_rn(0.95f, m2);
        float u2 = __fadd_rn(u1, c2);
        m2 = __fsub_rn(u2, r2);
        out[s * 5120 + b * 10 + t] = (m2 > 1.0f) ? 1.0f : 0.0f;  // spk2
        out[51200 + s * 5120 + b * 10 + t] = m2;                  // mem2
      }
    }
    __syncthreads();
  }
}

// ---------------------------------------------------------------------------
// Launch. Workspace (39.2 MB peak, aliased):
//   part [0, 30.72M)       — fc1 panel partials [15,512,1000] fp32
//   p1   [0, 16M)          — conv1 out (dead before fc1 writes part)
//   h    [30.72M, 39.1M)   — conv2 out (live through fc1)
//   wt   [39.1M, 39.2M)    — transposed conv2 weights (18432 fp32)
// ---------------------------------------------------------------------------
extern "C" void kernel_launch(void* const* d_in, const int* in_sizes, int n_in,
                              void* d_out, int out_size, void* d_ws,
                              size_t ws_size, hipStream_t stream) {
  const float* x   = (const float*)d_in[0];
  const float* c1w = (const float*)d_in[1];
  const float* c1b = (const float*)d_in[2];
  const float* c2w = (const float*)d_in[3];
  const float* c2b = (const float*)d_in[4];
  const float* f1w = (const float*)d_in[5];
  const float* f1b = (const float*)d_in[6];
  const float* f2w = (const float*)d_in[7];
  const float* f2b = (const float*)d_in[8];
  float* out = (float*)d_out;

  char* ws = (char*)d_ws;
  const size_t PART_B = (size_t)15 * 512 * 1000 * 4;  // 30.72 MB
  const size_t H_B    = (size_t)512 * 4096 * 4;       // 8.39 MB
  float* part = (float*)(ws);
  float* p1   = (float*)(ws);                          // alias (dead early)
  float* h    = (float*)(ws + PART_B);
  float* wt   = (float*)(ws + PART_B + H_B);

  conv2_wt<<<72, 256, 0, stream>>>(c2w, wt);
  conv1_pool<<<512, 256, 0, stream>>>(x, c1w, c1b, p1);
  conv2_pool<<<512, 256, 0, stream>>>(p1, wt, c2b, h);
  fc1_panel<<<dim3(4, 8, 15), 128, 0, stream>>>(h, f1w, part);
  snn_loop<<<512, 256, 0, stream>>>(part, f1b, f2w, f2b, out);
}